// Round 1
// baseline (92.432 us; speedup 1.0000x reference)
//
#include <hip/hip_runtime.h>
#include <math.h>

#define M_ANCHORS 76725
#define BATCH     16
#define N_GT      100
#define MATCH_IOU  0.5f
#define IGNORE_IOU 0.4f

__global__ __launch_bounds__(256) void retina_encode_kernel(
    const float* __restrict__ anchors,   // [M_ANCHORS, 4] (x, y, w, h)
    const float* __restrict__ gt,        // [BATCH, N_GT, 5] (x, y, w, h, cls)
    float* __restrict__ out)             // [BATCH, M_ANCHORS, 5]
{
    __shared__ float s_gx1[N_GT];
    __shared__ float s_gy1[N_GT];
    __shared__ float s_gx2[N_GT];
    __shared__ float s_gy2[N_GT];
    __shared__ float s_garea[N_GT];
    __shared__ float s_raw[N_GT * 5];

    const int b = blockIdx.y;
    const int a = blockIdx.x * blockDim.x + threadIdx.x;

    // Cooperative, coalesced load of this batch's GT boxes (500 floats).
    for (int i = threadIdx.x; i < N_GT * 5; i += blockDim.x)
        s_raw[i] = gt[b * (N_GT * 5) + i];
    __syncthreads();
    if (threadIdx.x < N_GT) {
        const int j = threadIdx.x;
        const float gx = s_raw[j * 5 + 0];
        const float gy = s_raw[j * 5 + 1];
        const float gw = s_raw[j * 5 + 2];
        const float gh = s_raw[j * 5 + 3];
        s_gx1[j] = gx;
        s_gy1[j] = gy;
        s_gx2[j] = gx + gw;
        s_gy2[j] = gy + gh;
        s_garea[j] = gw * gh;
    }
    __syncthreads();

    if (a >= M_ANCHORS) return;

    // Coalesced float4 anchor load.
    const float4 av = *reinterpret_cast<const float4*>(anchors + (size_t)a * 4);
    const float ax1 = av.x, ay1 = av.y, aw = av.z, ah = av.w;
    const float ax2 = ax1 + aw;
    const float ay2 = ay1 + ah;
    const float aarea = aw * ah;

    // IoU max + first-occurrence argmax (strict > replicates np.argmax).
    float best = -1.0f;
    int bidx = 0;
    #pragma unroll 4
    for (int j = 0; j < N_GT; ++j) {
        float iw = fminf(ax2, s_gx2[j]) - fmaxf(ax1, s_gx1[j]);
        iw = fmaxf(iw, 0.0f);
        float ih = fminf(ay2, s_gy2[j]) - fmaxf(ay1, s_gy1[j]);
        ih = fmaxf(ih, 0.0f);
        const float inter = iw * ih;
        const float uni = aarea + s_garea[j] - inter;
        // IEEE fp32 division (default hipcc codegen) to match numpy rounding.
        const float iou = (uni > 0.0f) ? (inter / uni) : 0.0f;
        if (iou > best) { best = iou; bidx = j; }
    }

    // Gather matched GT from LDS.
    const float mx   = s_raw[bidx * 5 + 0];
    const float my   = s_raw[bidx * 5 + 1];
    const float mw   = s_raw[bidx * 5 + 2];
    const float mh   = s_raw[bidx * 5 + 3];
    const float mcls = s_raw[bidx * 5 + 4];

    const float acx = ax1 + 0.5f * aw;
    const float acy = ay1 + 0.5f * ah;
    const float gcx = mx + 0.5f * mw;
    const float gcy = my + 0.5f * mh;

    // Same op order as reference: (delta / anchor_dim) / variance.
    float t0 = ((gcx - acx) / aw) / 0.1f;
    float t1 = ((gcy - acy) / ah) / 0.1f;
    float t2 = logf(mw / aw) / 0.2f;
    float t3 = logf(mh / ah) / 0.2f;

    const bool pos = (best >= MATCH_IOU);
    const bool neg = (best < IGNORE_IOU);
    float cls = pos ? mcls : -1.0f;          // BACKGROUND_CLASS
    if (!pos && !neg) cls = -2.0f;           // IGNORE_CLASS

    if (isnan(t0) || isnan(t1) || isnan(t2) || isnan(t3) || isnan(cls)) {
        t0 = t1 = t2 = t3 = cls = -2.0f;
    }

    float* o = out + ((size_t)b * M_ANCHORS + a) * 5;
    o[0] = t0;
    o[1] = t1;
    o[2] = t2;
    o[3] = t3;
    o[4] = cls;
}

extern "C" void kernel_launch(void* const* d_in, const int* in_sizes, int n_in,
                              void* d_out, int out_size, void* d_ws, size_t ws_size,
                              hipStream_t stream) {
    const float* anchors = (const float*)d_in[0];  // [76725, 4]
    const float* gt      = (const float*)d_in[1];  // [16, 100, 5]
    float* out           = (float*)d_out;          // [16, 76725, 5]

    const dim3 block(256, 1, 1);
    const dim3 grid((M_ANCHORS + 255) / 256, BATCH, 1);
    retina_encode_kernel<<<grid, block, 0, stream>>>(anchors, gt, out);
}

// Round 2
// 79.161 us; speedup vs baseline: 1.1677x; 1.1677x over previous
//
#include <hip/hip_runtime.h>
#include <math.h>

#define M_ANCHORS 76725
#define BATCH     16
#define N_GT      100
#define MATCH_IOU  0.5f
#define IGNORE_IOU 0.4f

// IoU argmax without per-candidate division:
//   iou = inter / (S - inter), S = a_area + g_area  (>0 always: w,h > 0)
//   iou_a > iou_b  <=>  inter_a * S_b > inter_b * S_a   (inter*inter cancels)
// numpy argmaxes over ROUNDED fp32 quotients; the cross-mult compares (near-)
// exact ratios. They can only disagree when two candidates sit within
// ~2.4e-7 relative of each other, so we flag any comparison with
// |Pj - Pb| <= 4e-6 * Pb (with a -1e-33 bias so the common exact 0-vs-0 tie
// never flags; exact ties keep the first index, matching np.argmax) and let
// flagged threads (expected: ~0 per launch) redo the loop with exact IEEE
// divisions replicating reference rounding.
__global__ __launch_bounds__(256) void retina_encode_kernel(
    const float* __restrict__ anchors,   // [M_ANCHORS, 4] (x, y, w, h)
    const float* __restrict__ gt,        // [BATCH, N_GT, 5] (x, y, w, h, cls)
    float* __restrict__ out)             // [BATCH, M_ANCHORS, 5]
{
#pragma clang fp contract(off)
    __shared__ float4 s_box[N_GT];       // x1, y1, x2, y2
    __shared__ float  s_ga[N_GT];        // g_area
    __shared__ float  s_raw[N_GT * 5];   // raw gt rows (for matched gather)

    const int b = blockIdx.y;
    const int a = blockIdx.x * blockDim.x + threadIdx.x;

    for (int i = threadIdx.x; i < N_GT * 5; i += blockDim.x)
        s_raw[i] = gt[b * (N_GT * 5) + i];
    __syncthreads();
    if (threadIdx.x < N_GT) {
        const int j = threadIdx.x;
        const float gx = s_raw[j * 5 + 0];
        const float gy = s_raw[j * 5 + 1];
        const float gw = s_raw[j * 5 + 2];
        const float gh = s_raw[j * 5 + 3];
        s_box[j] = make_float4(gx, gy, gx + gw, gy + gh);
        s_ga[j]  = gw * gh;
    }
    __syncthreads();

    if (a >= M_ANCHORS) return;

    const float4 av = *reinterpret_cast<const float4*>(anchors + (size_t)a * 4);
    const float ax1 = av.x, ay1 = av.y, aw = av.z, ah = av.w;
    const float ax2 = ax1 + aw;
    const float ay2 = ay1 + ah;
    const float aarea = aw * ah;

    float bestInter = 0.0f;   // ratio 0
    float bestS     = 1.0f;   // any positive
    int   bidx      = 0;
    int   flagged   = 0;

    #pragma unroll 10
    for (int j = 0; j < N_GT; ++j) {
        const float4 g = s_box[j];
        float iw = fminf(ax2, g.z) - fmaxf(ax1, g.x);
        iw = fmaxf(iw, 0.0f);
        float ih = fminf(ay2, g.w) - fmaxf(ay1, g.y);
        ih = fmaxf(ih, 0.0f);
        const float inter = iw * ih;
        const float S  = aarea + s_ga[j];
        const float pj = inter * bestS;
        const float pb = bestInter * S;
        const float d  = pj - pb;
        const float tol = fmaf(4e-6f, pb, -1e-33f);  // <0 when pb==0
        flagged |= (fabsf(d) <= tol);
        if (d > 0.0f) { bestInter = inter; bestS = S; bidx = j; }
    }

    float M;  // max_iou, rounded exactly as the reference rounds it
    if (!flagged) {
        // uni = fl(fl(A+G) - inter), then IEEE division — reference order.
        M = bestInter / (bestS - bestInter);
    } else {
        // Rare near-tie fallback: exact reference semantics with divisions.
        float best = -1.0f;
        bidx = 0;
        for (int j = 0; j < N_GT; ++j) {
            const float4 g = s_box[j];
            float iw = fminf(ax2, g.z) - fmaxf(ax1, g.x);
            iw = fmaxf(iw, 0.0f);
            float ih = fminf(ay2, g.w) - fmaxf(ay1, g.y);
            ih = fmaxf(ih, 0.0f);
            const float inter = iw * ih;
            const float uni = (aarea + s_ga[j]) - inter;
            const float iou = (uni > 0.0f) ? (inter / uni) : 0.0f;
            if (iou > best) { best = iou; bidx = j; }
        }
        M = best;
    }

    const float mx   = s_raw[bidx * 5 + 0];
    const float my   = s_raw[bidx * 5 + 1];
    const float mw   = s_raw[bidx * 5 + 2];
    const float mh   = s_raw[bidx * 5 + 3];
    const float mcls = s_raw[bidx * 5 + 4];

    const float acx = ax1 + 0.5f * aw;
    const float acy = ay1 + 0.5f * ah;
    const float gcx = mx + 0.5f * mw;
    const float gcy = my + 0.5f * mh;

    // Same op order as reference: (delta / anchor_dim) / variance.
    float t0 = ((gcx - acx) / aw) / 0.1f;
    float t1 = ((gcy - acy) / ah) / 0.1f;
    float t2 = logf(mw / aw) / 0.2f;
    float t3 = logf(mh / ah) / 0.2f;

    const bool pos = (M >= MATCH_IOU);
    const bool neg = (M < IGNORE_IOU);
    float cls = pos ? mcls : -1.0f;          // BACKGROUND_CLASS
    if (!pos && !neg) cls = -2.0f;           // IGNORE_CLASS

    if (isnan(t0) || isnan(t1) || isnan(t2) || isnan(t3) || isnan(cls)) {
        t0 = t1 = t2 = t3 = cls = -2.0f;
    }

    float* o = out + ((size_t)b * M_ANCHORS + a) * 5;
    o[0] = t0;
    o[1] = t1;
    o[2] = t2;
    o[3] = t3;
    o[4] = cls;
}

extern "C" void kernel_launch(void* const* d_in, const int* in_sizes, int n_in,
                              void* d_out, int out_size, void* d_ws, size_t ws_size,
                              hipStream_t stream) {
    const float* anchors = (const float*)d_in[0];  // [76725, 4]
    const float* gt      = (const float*)d_in[1];  // [16, 100, 5]
    float* out           = (float*)d_out;          // [16, 76725, 5]

    const dim3 block(256, 1, 1);
    const dim3 grid((M_ANCHORS + 255) / 256, BATCH, 1);
    retina_encode_kernel<<<grid, block, 0, stream>>>(anchors, gt, out);
}

// Round 3
// 76.580 us; speedup vs baseline: 1.2070x; 1.0337x over previous
//
#include <hip/hip_runtime.h>
#include <math.h>

#define M_ANCHORS 76725
#define BATCH     16
#define N_GT      100
#define HALF_GT   50
#define MATCH_IOU  0.5f
#define IGNORE_IOU 0.4f

// Two threads per anchor: even lane handles GT j in [0,50), odd lane [50,100).
// IoU argmax via cross-multiplication (iou_a > iou_b <=> inter_a*S_b >
// inter_b*S_a, S = a_area + g_area > 0), with a near-tie band (4e-6 relative)
// that falls back to exact IEEE-division reference semantics for flagged
// threads (~never). Ties keep the lower index, matching np.argmax.
__global__ __launch_bounds__(256) void retina_encode_kernel(
    const float* __restrict__ anchors,   // [M_ANCHORS, 4] (x, y, w, h)
    const float* __restrict__ gt,        // [BATCH, N_GT, 5] (x, y, w, h, cls)
    float* __restrict__ out)             // [BATCH, M_ANCHORS, 5]
{
#pragma clang fp contract(off)
    __shared__ float4 s_box[N_GT];       // x1, y1, x2, y2
    __shared__ float  s_ga[N_GT];        // g_area
    __shared__ float  s_raw[N_GT * 5];   // raw gt rows (for matched gather)

    const int b = blockIdx.y;
    const int t = threadIdx.x;
    const int a = blockIdx.x * 128 + (t >> 1);
    const int half = t & 1;

    for (int i = t; i < N_GT * 5; i += blockDim.x)
        s_raw[i] = gt[b * (N_GT * 5) + i];
    __syncthreads();
    if (t < N_GT) {
        const float gx = s_raw[t * 5 + 0];
        const float gy = s_raw[t * 5 + 1];
        const float gw = s_raw[t * 5 + 2];
        const float gh = s_raw[t * 5 + 3];
        s_box[t] = make_float4(gx, gy, gx + gw, gy + gh);
        s_ga[t]  = gw * gh;
    }
    __syncthreads();

    if (a >= M_ANCHORS) return;

    const float4 av = *reinterpret_cast<const float4*>(anchors + (size_t)a * 4);
    const float ax1 = av.x, ay1 = av.y, aw = av.z, ah = av.w;
    const float ax2 = ax1 + aw;
    const float ay2 = ay1 + ah;
    const float aarea = aw * ah;

    const int jbase = half ? HALF_GT : 0;

    float bI = 0.0f;      // best inter (always >= 0 after loop)
    float bS = 1.0f;      // best S (any positive for the zero candidate)
    int   bj = jbase;
    bool  flag = false;

    #pragma unroll 10
    for (int jj = 0; jj < HALF_GT; ++jj) {
        const int j = jbase + jj;
        const float4 g = s_box[j];
        // iw clamped; ih unclamped: if ih_raw < 0 then inter <= 0 and can
        // neither win nor flag (|d| >= pb > tol). Winner always has both
        // positive, so its inter is bit-identical to the reference's.
        float iw = fmaxf(fminf(ax2, g.z) - fmaxf(ax1, g.x), 0.0f);
        float ih = fminf(ay2, g.w) - fmaxf(ay1, g.y);
        const float inter = iw * ih;
        const float S   = aarea + s_ga[j];
        const float pb  = bI * S;
        const float d   = fmaf(inter, bS, -pb);       // inter*bS - bI*S
        const float tol = fmaf(4e-6f, pb, -1e-33f);   // < 0 when pb == 0
        flag = flag | (fabsf(d) <= tol);
        if (d > 0.0f) { bI = inter; bS = S; bj = j; }
    }

    // Pairwise reduce across the two halves (partner = lane ^ 1).
    const float oI = __shfl_xor(bI, 1);
    const float oS = __shfl_xor(bS, 1);
    const int   oj = __shfl_xor(bj, 1);
    const int   of = __shfl_xor((int)flag, 1);

    if (half) return;  // odd lanes contributed via shfl; done.

    // Incumbent = low half (mine), challenger = high half (partner).
    bool anyflag = flag | (of != 0);
    const float pA = oI * bS;          // challenger cross-product
    const float pB = bI * oS;          // incumbent cross-product
    const float dd = pA - pB;
    const float ptol = fmaf(4e-6f, fmaxf(pA, pB), -1e-33f);
    anyflag = anyflag | (fabsf(dd) <= ptol);

    float BI = bI, BS = bS;
    int   bidx = bj;
    if (dd > 0.0f) { BI = oI; BS = oS; bidx = oj; }

    float M;  // max_iou rounded exactly as the reference rounds it
    if (!anyflag) {
        M = BI / (BS - BI);
    } else {
        // Rare near-tie fallback: exact reference semantics over all 100 GTs.
        float best = -1.0f;
        bidx = 0;
        for (int j = 0; j < N_GT; ++j) {
            const float4 g = s_box[j];
            float iw = fmaxf(fminf(ax2, g.z) - fmaxf(ax1, g.x), 0.0f);
            float ih = fmaxf(fminf(ay2, g.w) - fmaxf(ay1, g.y), 0.0f);
            const float inter = iw * ih;
            const float uni = (aarea + s_ga[j]) - inter;
            const float iou = (uni > 0.0f) ? (inter / uni) : 0.0f;
            if (iou > best) { best = iou; bidx = j; }
        }
        M = best;
    }

    const float mx   = s_raw[bidx * 5 + 0];
    const float my   = s_raw[bidx * 5 + 1];
    const float mw   = s_raw[bidx * 5 + 2];
    const float mh   = s_raw[bidx * 5 + 3];
    const float mcls = s_raw[bidx * 5 + 4];

    const float acx = ax1 + 0.5f * aw;
    const float acy = ay1 + 0.5f * ah;
    const float gcx = mx + 0.5f * mw;
    const float gcy = my + 0.5f * mh;

    // Same op order as reference: (delta / anchor_dim) / variance.
    float t0 = ((gcx - acx) / aw) / 0.1f;
    float t1 = ((gcy - acy) / ah) / 0.1f;
    float t2 = logf(mw / aw) / 0.2f;
    float t3 = logf(mh / ah) / 0.2f;

    const bool pos = (M >= MATCH_IOU);
    const bool neg = (M < IGNORE_IOU);
    float cls = pos ? mcls : -1.0f;          // BACKGROUND_CLASS
    if (!pos && !neg) cls = -2.0f;           // IGNORE_CLASS

    if (isnan(t0) || isnan(t1) || isnan(t2) || isnan(t3) || isnan(cls)) {
        t0 = t1 = t2 = t3 = cls = -2.0f;
    }

    float* o = out + ((size_t)b * M_ANCHORS + a) * 5;
    o[0] = t0;
    o[1] = t1;
    o[2] = t2;
    o[3] = t3;
    o[4] = cls;
}

extern "C" void kernel_launch(void* const* d_in, const int* in_sizes, int n_in,
                              void* d_out, int out_size, void* d_ws, size_t ws_size,
                              hipStream_t stream) {
    const float* anchors = (const float*)d_in[0];  // [76725, 4]
    const float* gt      = (const float*)d_in[1];  // [16, 100, 5]
    float* out           = (float*)d_out;          // [16, 76725, 5]

    const dim3 block(256, 1, 1);
    const dim3 grid((M_ANCHORS + 127) / 128, BATCH, 1);  // 600 x 16
    retina_encode_kernel<<<grid, block, 0, stream>>>(anchors, gt, out);
}